// Round 1
// baseline (3960.897 us; speedup 1.0000x reference)
//
#include <hip/hip_runtime.h>
#include <hip/hip_bf16.h>
#include <stdint.h>
#include <stddef.h>

// LSTM: T=512, B=64, I=512, H=512.
// Phase 1: xproj[t*64+b][g*512+c] = bias[g][c] + sum_k x[t,b,k]*W_g[c,k]   (bf16 MFMA GEMM)
// Phase 2: 32 persistent WGs, each owns 16 h-cols; Wh slice resident in LDS;
//          per-step cross-WG h broadcast via global + per-WG release/acquire flags.

#define T_STEPS 512
#define BATCH   64
#define HDIM    512
#define NWG     32

using short8 = __attribute__((ext_vector_type(8))) short;  // 8 bf16 (4 VGPR) MFMA operand
using f32x4  = __attribute__((ext_vector_type(4))) float;  // MFMA accumulator

__device__ __forceinline__ void gload_lds16(const void* g, void* l) {
  __builtin_amdgcn_global_load_lds((const __attribute__((address_space(1))) void*)g,
                                   (__attribute__((address_space(3))) void*)l, 16, 0, 0);
}
__device__ __forceinline__ float sigf(float x) { return 1.0f / (1.0f + __expf(-x)); }
__device__ __forceinline__ float tanh_fast(float x) {
  x = fminf(fmaxf(x, -15.0f), 15.0f);
  float e = __expf(2.0f * x);
  return (e - 1.0f) / (e + 1.0f);
}
__device__ __forceinline__ short bfb(float f) {
  __hip_bfloat16 h = __float2bfloat16(f);
  short s; __builtin_memcpy(&s, &h, 2); return s;
}

// ---------------- prep: build Wx_bt/Wh_bt [2048][512] bf16, bias[2048], zero hbuf+flags
__global__ __launch_bounds__(256) void k_prep(
    const float* __restrict__ Wf, const float* __restrict__ bf_,
    const float* __restrict__ Wi, const float* __restrict__ bi,
    const float* __restrict__ Wg, const float* __restrict__ bg,
    const float* __restrict__ Wo, const float* __restrict__ bo,
    __hip_bfloat16* __restrict__ wxbt, __hip_bfloat16* __restrict__ whbt,
    float* __restrict__ bias, __hip_bfloat16* __restrict__ hbuf, int* __restrict__ flags)
{
  int idx = blockIdx.x * 256 + threadIdx.x;   // 4096 blocks -> 1,048,576 = 2048*512
  int row = idx >> 9;                          // 0..2047 (gate-major)
  int k   = idx & 511;
  int g = row >> 9, r = row & 511;
  const float* W = (g == 0) ? Wf : (g == 1) ? Wi : (g == 2) ? Wg : Wo;
  const float* B = (g == 0) ? bf_ : (g == 1) ? bi : (g == 2) ? bg : bo;
  wxbt[(size_t)row * 512 + k] = __float2bfloat16(W[(size_t)r * 1024 + k]);
  whbt[(size_t)row * 512 + k] = __float2bfloat16(W[(size_t)r * 1024 + 512 + k]);
  if (k == 0) bias[row] = B[r];
  if (idx < 2 * BATCH * HDIM) hbuf[idx] = __float2bfloat16(0.0f);  // both h buffers
  if (idx < NWG) flags[idx] = 0;
}

// ---------------- convert x to bf16, 8 elems/thread
__global__ __launch_bounds__(256) void k_convx(const float* __restrict__ x,
                                               __hip_bfloat16* __restrict__ xbf)
{
  int idx = blockIdx.x * 256 + threadIdx.x;    // 8192 blocks -> 2,097,152 * 8 = 16,777,216
  const float4* p = (const float4*)x + (size_t)idx * 2;
  float4 a = p[0], b = p[1];
  short8 o;
  o[0]=bfb(a.x); o[1]=bfb(a.y); o[2]=bfb(a.z); o[3]=bfb(a.w);
  o[4]=bfb(b.x); o[5]=bfb(b.y); o[6]=bfb(b.z); o[7]=bfb(b.w);
  *(short8*)((short*)xbf + (size_t)idx * 8) = o;
}

// ---------------- phase 1 GEMM: [32768,512] x [512 -> 2048] (B^T layout), +bias, bf16 out
// 128x128 tile, BK=64, 4 waves, global_load_lds w16, XOR-swizzled LDS.
__global__ __launch_bounds__(256) void k_xproj(
    const __hip_bfloat16* __restrict__ xbf,   // [32768][512]
    const __hip_bfloat16* __restrict__ wxbt,  // [2048][512]
    const float* __restrict__ bias,           // [2048]
    __hip_bfloat16* __restrict__ xproj)       // [32768][2048]
{
  __shared__ __align__(16) short aT[128 * 64];
  __shared__ __align__(16) short bT[128 * 64];
  const int tid = threadIdx.x, lane = tid & 63, wave = tid >> 6;
  const int m0 = blockIdx.y * 128, n0 = blockIdx.x * 128;
  const int wr = wave >> 1, wc = wave & 1;

  f32x4 acc[4][4] = {};

  for (int s = 0; s < 8; ++s) {               // K=512, BK=64
    __syncthreads();                           // previous compute done before overwrite
    const int kbyte = s * 128;                 // 64 bf16 = 128 B per row
#pragma unroll
    for (int it = 0; it < 4; ++it) {
      int flat = it * 256 + tid;               // 0..1023
      int row = flat >> 3, gr = flat & 7;      // row 0..127, granule(16B) 0..7
      int sgr = gr ^ (row & 7);                // pre-swizzled global source (m173 pattern)
      const char* ga = (const char*)xbf  + (size_t)(m0 + row) * 1024 + kbyte + sgr * 16;
      const char* gb = (const char*)wxbt + (size_t)(n0 + row) * 1024 + kbyte + sgr * 16;
      char* ldst = (char*)0 /*placeholder*/;
      (void)ldst;
      gload_lds16(ga, (char*)aT + (it * 256 + wave * 64) * 16);
      gload_lds16(gb, (char*)bT + (it * 256 + wave * 64) * 16);
    }
    __syncthreads();                           // staging landed
#pragma unroll
    for (int kk2 = 0; kk2 < 2; ++kk2) {        // BK=64 = 2 x K32
      short8 af[4], bfr[4];
#pragma unroll
      for (int mt = 0; mt < 4; ++mt) {
        int r = wr * 64 + mt * 16 + (lane & 15);
        int g = (kk2 * 4 + (lane >> 4)) ^ (r & 7);
        af[mt] = *(const short8*)((const char*)aT + r * 128 + g * 16);
      }
#pragma unroll
      for (int nt = 0; nt < 4; ++nt) {
        int r = wc * 64 + nt * 16 + (lane & 15);
        int g = (kk2 * 4 + (lane >> 4)) ^ (r & 7);
        bfr[nt] = *(const short8*)((const char*)bT + r * 128 + g * 16);
      }
#pragma unroll
      for (int mt = 0; mt < 4; ++mt)
#pragma unroll
        for (int nt = 0; nt < 4; ++nt)
          acc[mt][nt] = __builtin_amdgcn_mfma_f32_16x16x32_bf16(af[mt], bfr[nt], acc[mt][nt], 0, 0, 0);
    }
  }
  // epilogue: + bias, store bf16. C layout: col=lane&15, row=(lane>>4)*4+i
#pragma unroll
  for (int nt = 0; nt < 4; ++nt) {
    int n = n0 + wc * 64 + nt * 16 + (lane & 15);
    float bv = bias[n];
#pragma unroll
    for (int mt = 0; mt < 4; ++mt)
#pragma unroll
      for (int i = 0; i < 4; ++i) {
        int m = m0 + wr * 64 + mt * 16 + (lane >> 4) * 4 + i;
        xproj[(size_t)m * 2048 + n] = __float2bfloat16(acc[mt][nt][i] + bv);
      }
  }
}

// ---------------- phase 2: persistent recurrence. 32 WGs x 4 waves.
// WG j owns h-cols [j*16, j*16+16); wave w owns batch rows [w*16, w*16+16).
__global__ __launch_bounds__(256, 1) void k_recur(
    const __hip_bfloat16* __restrict__ xproj, // [32768][2048]
    const __hip_bfloat16* __restrict__ whbt,  // [2048][512]
    __hip_bfloat16* __restrict__ hbuf,        // [2][64][512]
    float* __restrict__ out,                  // outputs[512][64][512] | hx[64][512] | cx[64][512]
    int* __restrict__ flags)                  // [32] step counters
{
  __shared__ __align__(16) short wlds[64 * 512];   // 64 KB, rows: g*16+c, XOR-swizzled
  const int tid = threadIdx.x, lane = tid & 63, wave = tid >> 6;
  const int j = blockIdx.x;
  const int hc0 = j * 16;
  const int col = lane & 15;
  const int mrow = (lane >> 4) * 4;

  // stage Wh slice once: LDS[row=g*16+c][gr] = Wh_bt[g*512+hc0+c][gr ^ (row&7)]
  for (int it = 0; it < 16; ++it) {
    int flat = it * 256 + tid;                // 0..4095 granules
    int row = flat >> 6, gr = flat & 63;      // row 0..63 (=1024B), gr 0..63
    int g = row >> 4, c = row & 15;
    int sgr = gr ^ (row & 7);
    const char* gsrc = (const char*)whbt + ((size_t)(g * 512 + hc0 + c)) * 1024 + sgr * 16;
    gload_lds16(gsrc, (char*)wlds + (it * 256 + wave * 64) * 16);
  }
  __syncthreads();

  float c_state[4] = {0.f, 0.f, 0.f, 0.f};
  float* out_hx = out + (size_t)T_STEPS * BATCH * HDIM;
  float* out_cx = out_hx + BATCH * HDIM;

  for (int t = 0; t < T_STEPS; ++t) {
    const int cur = t & 1;
    // xproj loads first (independent of flags) so they fly during the spin
    float xp[4][4];
    const __hip_bfloat16* xprow = xproj + ((size_t)t * 64) * 2048;
#pragma unroll
    for (int g = 0; g < 4; ++g)
#pragma unroll
      for (int i = 0; i < 4; ++i) {
        int row = wave * 16 + mrow + i;
        xp[g][i] = __bfloat162float(xprow[(size_t)row * 2048 + g * 512 + hc0 + col]);
      }
    // wait for all producers to have published h^t (flag >= t). t=0 trivially ready.
    if (t > 0 && lane < NWG) {
      while (__hip_atomic_load(&flags[lane], __ATOMIC_ACQUIRE, __HIP_MEMORY_SCOPE_AGENT) < t)
        __builtin_amdgcn_s_sleep(1);
    }
    // A fragments: h^t rows wave*16..+15, full K=512
    const char* hcur = (const char*)hbuf + cur * (BATCH * HDIM * 2);
    short8 af[16];
#pragma unroll
    for (int kk = 0; kk < 16; ++kk) {
      int r = wave * 16 + (lane & 15);
      af[kk] = *(const short8*)(hcur + r * 1024 + kk * 64 + (lane >> 4) * 16);
    }
    f32x4 acc[4] = {};
#pragma unroll
    for (int kk = 0; kk < 16; ++kk) {
#pragma unroll
      for (int g = 0; g < 4; ++g) {
        int r = g * 16 + col;
        int gran = (kk * 4 + (lane >> 4)) ^ (r & 7);
        short8 bfr = *(const short8*)((const char*)wlds + r * 1024 + gran * 16);
        acc[g] = __builtin_amdgcn_mfma_f32_16x16x32_bf16(af[kk], bfr, acc[g], 0, 0, 0);
      }
    }
    // epilogue: gates, state update, stores
    __hip_bfloat16* hnxt = (__hip_bfloat16*)((char*)hbuf + (cur ^ 1) * (BATCH * HDIM * 2));
#pragma unroll
    for (int i = 0; i < 4; ++i) {
      int row = wave * 16 + mrow + i;
      float pf = acc[0][i] + xp[0][i];
      float pi = acc[1][i] + xp[1][i];
      float pg = acc[2][i] + xp[2][i];
      float po = acc[3][i] + xp[3][i];
      float fg = sigf(pf), ig = sigf(pi), gg = tanh_fast(pg), og = sigf(po);
      float cn = fg * c_state[i] + ig * gg;
      c_state[i] = cn;
      float hn = og * tanh_fast(cn);
      out[((size_t)t * BATCH + row) * HDIM + hc0 + col] = hn;
      hnxt[row * HDIM + hc0 + col] = __float2bfloat16(hn);
      if (t == T_STEPS - 1) {
        out_hx[row * HDIM + hc0 + col] = hn;
        out_cx[row * HDIM + hc0 + col] = cn;
      }
    }
    __syncthreads();  // all waves' h writes done before publishing
    if (tid == 0)
      __hip_atomic_store(&flags[j], t + 1, __ATOMIC_RELEASE, __HIP_MEMORY_SCOPE_AGENT);
  }
}

extern "C" void kernel_launch(void* const* d_in, const int* in_sizes, int n_in,
                              void* d_out, int out_size, void* d_ws, size_t ws_size,
                              hipStream_t stream) {
  const float* x   = (const float*)d_in[0];
  const float* Wf  = (const float*)d_in[1];
  const float* bf_ = (const float*)d_in[2];
  const float* Wi  = (const float*)d_in[3];
  const float* bi  = (const float*)d_in[4];
  const float* Wg  = (const float*)d_in[5];
  const float* bg  = (const float*)d_in[6];
  const float* Wo  = (const float*)d_in[7];
  const float* bo  = (const float*)d_in[8];

  char* ws = (char*)d_ws;
  __hip_bfloat16* xbf   = (__hip_bfloat16*)(ws);                 // 33,554,432 B
  __hip_bfloat16* wxbt  = (__hip_bfloat16*)(ws + 33554432);      //  2,097,152 B
  __hip_bfloat16* whbt  = (__hip_bfloat16*)(ws + 35651584);      //  2,097,152 B
  float*          bias  = (float*)         (ws + 37748736);      //      8,192 B
  __hip_bfloat16* xproj = (__hip_bfloat16*)(ws + 37756928);      // 134,217,728 B
  __hip_bfloat16* hbuf  = (__hip_bfloat16*)(ws + 171974656);     //    131,072 B
  int*            flags = (int*)           (ws + 172105728);     //        128 B

  k_prep <<<4096, 256, 0, stream>>>(Wf, bf_, Wi, bi, Wg, bg, Wo, bo,
                                    wxbt, whbt, bias, hbuf, flags);
  k_convx<<<8192, 256, 0, stream>>>(x, xbf);
  k_xproj<<<dim3(16, 256), 256, 0, stream>>>(xbf, wxbt, bias, xproj);
  k_recur<<<NWG, 256, 0, stream>>>(xproj, whbt, hbuf, (float*)d_out, flags);
}

// Round 2
// 2976.477 us; speedup vs baseline: 1.3307x; 1.3307x over previous
//
#include <hip/hip_runtime.h>
#include <hip/hip_bf16.h>
#include <stdint.h>
#include <stddef.h>

// LSTM: T=512, B=64, I=512, H=512.
// Phase 1: xproj[t*64+b][g*512+c] = bias[g][c] + sum_k x[t,b,k]*W_g[c,k]   (bf16 MFMA GEMM)
// Phase 2: 32 persistent WGs, each owns 16 h-cols; Wh slice resident in LDS.
//          Cross-WG h broadcast + flags go through the device coherence point
//          via explicit sc0 sc1 loads/stores (NO compiler acquire/release --
//          agent-scope acquire = full-L2 buffer_inv per poll, which was the
//          7.5us/step pathology in round 1).

#define T_STEPS 512
#define BATCH   64
#define HDIM    512
#define NWG     32

using short8 = __attribute__((ext_vector_type(8))) short;  // 8 bf16 (4 VGPR) MFMA operand
using f32x4  = __attribute__((ext_vector_type(4))) float;  // MFMA accumulator
using int4v  = __attribute__((ext_vector_type(4))) int;

__device__ __forceinline__ void gload_lds16(const void* g, void* l) {
  __builtin_amdgcn_global_load_lds((const __attribute__((address_space(1))) void*)g,
                                   (__attribute__((address_space(3))) void*)l, 16, 0, 0);
}
__device__ __forceinline__ float sigf(float x) { return 1.0f / (1.0f + __expf(-x)); }
__device__ __forceinline__ float tanh_fast(float x) {
  x = fminf(fmaxf(x, -15.0f), 15.0f);
  float e = __expf(2.0f * x);
  return (e - 1.0f) / (e + 1.0f);
}
__device__ __forceinline__ short bfb(float f) {
  __hip_bfloat16 h = __float2bfloat16(f);
  short s; __builtin_memcpy(&s, &h, 2); return s;
}
__device__ __forceinline__ unsigned bfbits(float f) {
  __hip_bfloat16 h = __float2bfloat16(f);
  unsigned short s; __builtin_memcpy(&s, &h, 2); return (unsigned)s;
}

// ---------------- prep: build Wx_bt/Wh_bt [2048][512] bf16, bias[2048], zero hbuf+flags
__global__ __launch_bounds__(256) void k_prep(
    const float* __restrict__ Wf, const float* __restrict__ bf_,
    const float* __restrict__ Wi, const float* __restrict__ bi,
    const float* __restrict__ Wg, const float* __restrict__ bg,
    const float* __restrict__ Wo, const float* __restrict__ bo,
    __hip_bfloat16* __restrict__ wxbt, __hip_bfloat16* __restrict__ whbt,
    float* __restrict__ bias, __hip_bfloat16* __restrict__ hbuf, int* __restrict__ flags)
{
  int idx = blockIdx.x * 256 + threadIdx.x;   // 4096 blocks -> 1,048,576 = 2048*512
  int row = idx >> 9;                          // 0..2047 (gate-major)
  int k   = idx & 511;
  int g = row >> 9, r = row & 511;
  const float* W = (g == 0) ? Wf : (g == 1) ? Wi : (g == 2) ? Wg : Wo;
  const float* B = (g == 0) ? bf_ : (g == 1) ? bi : (g == 2) ? bg : bo;
  wxbt[(size_t)row * 512 + k] = __float2bfloat16(W[(size_t)r * 1024 + k]);
  whbt[(size_t)row * 512 + k] = __float2bfloat16(W[(size_t)r * 1024 + 512 + k]);
  if (k == 0) bias[row] = B[r];
  if (idx < 2 * BATCH * HDIM) hbuf[idx] = __float2bfloat16(0.0f);  // both h buffers
  if (idx < NWG) flags[idx] = 0;
}

// ---------------- convert x to bf16, 8 elems/thread
__global__ __launch_bounds__(256) void k_convx(const float* __restrict__ x,
                                               __hip_bfloat16* __restrict__ xbf)
{
  int idx = blockIdx.x * 256 + threadIdx.x;    // 8192 blocks -> 2,097,152 * 8 = 16,777,216
  const float4* p = (const float4*)x + (size_t)idx * 2;
  float4 a = p[0], b = p[1];
  short8 o;
  o[0]=bfb(a.x); o[1]=bfb(a.y); o[2]=bfb(a.z); o[3]=bfb(a.w);
  o[4]=bfb(b.x); o[5]=bfb(b.y); o[6]=bfb(b.z); o[7]=bfb(b.w);
  *(short8*)((short*)xbf + (size_t)idx * 8) = o;
}

// ---------------- phase 1 GEMM: [32768,512] x [512 -> 2048] (B^T layout), +bias, bf16 out
// 128x128 tile, BK=64, 4 waves, global_load_lds w16, XOR-swizzled LDS.
__global__ __launch_bounds__(256) void k_xproj(
    const __hip_bfloat16* __restrict__ xbf,   // [32768][512]
    const __hip_bfloat16* __restrict__ wxbt,  // [2048][512]
    const float* __restrict__ bias,           // [2048]
    __hip_bfloat16* __restrict__ xproj)       // [32768][2048]
{
  __shared__ __align__(16) short aT[128 * 64];
  __shared__ __align__(16) short bT[128 * 64];
  const int tid = threadIdx.x, lane = tid & 63, wave = tid >> 6;
  const int m0 = blockIdx.y * 128, n0 = blockIdx.x * 128;
  const int wr = wave >> 1, wc = wave & 1;

  f32x4 acc[4][4] = {};

  for (int s = 0; s < 8; ++s) {               // K=512, BK=64
    __syncthreads();                           // previous compute done before overwrite
    const int kbyte = s * 128;                 // 64 bf16 = 128 B per row
#pragma unroll
    for (int it = 0; it < 4; ++it) {
      int flat = it * 256 + tid;               // 0..1023
      int row = flat >> 3, gr = flat & 7;      // row 0..127, granule(16B) 0..7
      int sgr = gr ^ (row & 7);                // pre-swizzled global source (m173 pattern)
      const char* ga = (const char*)xbf  + (size_t)(m0 + row) * 1024 + kbyte + sgr * 16;
      const char* gb = (const char*)wxbt + (size_t)(n0 + row) * 1024 + kbyte + sgr * 16;
      gload_lds16(ga, (char*)aT + (it * 256 + wave * 64) * 16);
      gload_lds16(gb, (char*)bT + (it * 256 + wave * 64) * 16);
    }
    __syncthreads();                           // staging landed
#pragma unroll
    for (int kk2 = 0; kk2 < 2; ++kk2) {        // BK=64 = 2 x K32
      short8 af[4], bfr[4];
#pragma unroll
      for (int mt = 0; mt < 4; ++mt) {
        int r = wr * 64 + mt * 16 + (lane & 15);
        int g = (kk2 * 4 + (lane >> 4)) ^ (r & 7);
        af[mt] = *(const short8*)((const char*)aT + r * 128 + g * 16);
      }
#pragma unroll
      for (int nt = 0; nt < 4; ++nt) {
        int r = wc * 64 + nt * 16 + (lane & 15);
        int g = (kk2 * 4 + (lane >> 4)) ^ (r & 7);
        bfr[nt] = *(const short8*)((const char*)bT + r * 128 + g * 16);
      }
#pragma unroll
      for (int mt = 0; mt < 4; ++mt)
#pragma unroll
        for (int nt = 0; nt < 4; ++nt)
          acc[mt][nt] = __builtin_amdgcn_mfma_f32_16x16x32_bf16(af[mt], bfr[nt], acc[mt][nt], 0, 0, 0);
    }
  }
  // epilogue: + bias, store bf16. C layout: col=lane&15, row=(lane>>4)*4+i
#pragma unroll
  for (int nt = 0; nt < 4; ++nt) {
    int n = n0 + wc * 64 + nt * 16 + (lane & 15);
    float bv = bias[n];
#pragma unroll
    for (int mt = 0; mt < 4; ++mt)
#pragma unroll
      for (int i = 0; i < 4; ++i) {
        int m = m0 + wr * 64 + mt * 16 + (lane >> 4) * 4 + i;
        xproj[(size_t)m * 2048 + n] = __float2bfloat16(acc[mt][nt][i] + bv);
      }
  }
}

// ---------------- phase 2: persistent recurrence. 32 WGs x 4 waves.
// WG j owns h-cols [j*16, j*16+16); wave w owns batch rows [w*16, w*16+16).
// All cross-WG traffic (hbuf, flags) via sc0 sc1 (L1+L2 bypass -> coherent LLC).
__global__ __launch_bounds__(256, 1) void k_recur(
    const __hip_bfloat16* __restrict__ xproj, // [32768][2048]
    const __hip_bfloat16* __restrict__ whbt,  // [2048][512]
    __hip_bfloat16* __restrict__ hbuf,        // [2][64][512]
    float* __restrict__ out,                  // outputs[512][64][512] | hx[64][512] | cx[64][512]
    int* __restrict__ flags)                  // [32] step counters
{
  __shared__ __align__(16) short wlds[64 * 512];   // 64 KB, rows: g*16+c, XOR-swizzled
  const int tid = threadIdx.x, lane = tid & 63, wave = tid >> 6;
  const int j = blockIdx.x;
  const int hc0 = j * 16;
  const int col = lane & 15;
  const int mrow = (lane >> 4) * 4;

  // stage Wh slice once: LDS[row=g*16+c][gr] = Wh_bt[g*512+hc0+c][gr ^ (row&7)]
  for (int it = 0; it < 16; ++it) {
    int flat = it * 256 + tid;                // 0..4095 granules
    int row = flat >> 6, gr = flat & 63;      // row 0..63 (=1024B), gr 0..63
    int g = row >> 4, c = row & 15;
    int sgr = gr ^ (row & 7);
    const char* gsrc = (const char*)whbt + ((size_t)(g * 512 + hc0 + c)) * 1024 + sgr * 16;
    gload_lds16(gsrc, (char*)wlds + (it * 256 + wave * 64) * 16);
  }
  __syncthreads();

  float c_state[4] = {0.f, 0.f, 0.f, 0.f};
  float* out_hx = out + (size_t)T_STEPS * BATCH * HDIM;
  float* out_cx = out_hx + BATCH * HDIM;

  for (int t = 0; t < T_STEPS; ++t) {
    const int cur = t & 1;
    // xproj loads first (independent of flags) so they fly during the spin
    float xp[4][4];
    const __hip_bfloat16* xprow = xproj + ((size_t)t * 64) * 2048;
#pragma unroll
    for (int g = 0; g < 4; ++g)
#pragma unroll
      for (int i = 0; i < 4; ++i) {
        int row = wave * 16 + mrow + i;
        xp[g][i] = __bfloat162float(xprow[(size_t)row * 2048 + g * 512 + hc0 + col]);
      }
    // wait for all producers to have published h^t (flag >= t). t=0 trivially ready.
    // Relaxed sc0 sc1 poll -- NO acquire (no L2 invalidate storms).
    if (t > 0 && lane < NWG) {
      const int* fp = &flags[lane];
      int fv;
      do {
        asm volatile("global_load_dword %0, %1, off sc0 sc1\n\t"
                     "s_waitcnt vmcnt(0)"
                     : "=v"(fv) : "v"(fp) : "memory");
      } while (fv < t);
    }
    // A fragments: h^t rows wave*16..+15, full K=512, via coherent sc0 sc1 loads
    const char* hcur = (const char*)hbuf + cur * (BATCH * HDIM * 2);
    int4v araw[16];
#pragma unroll
    for (int kk = 0; kk < 16; ++kk) {
      int r = wave * 16 + (lane & 15);
      const void* ap = hcur + r * 1024 + kk * 64 + (lane >> 4) * 16;
      asm volatile("global_load_dwordx4 %0, %1, off sc0 sc1"
                   : "=v"(araw[kk]) : "v"(ap) : "memory");
    }
    asm volatile("s_waitcnt vmcnt(0)" ::: "memory");
    __builtin_amdgcn_sched_barrier(0);   // rule #18: keep MFMA after the drain

    f32x4 acc[4] = {};
#pragma unroll
    for (int kk = 0; kk < 16; ++kk) {
      short8 af = __builtin_bit_cast(short8, araw[kk]);
#pragma unroll
      for (int g = 0; g < 4; ++g) {
        int r = g * 16 + col;
        int gran = (kk * 4 + (lane >> 4)) ^ (r & 7);
        short8 bfr = *(const short8*)((const char*)wlds + r * 1024 + gran * 16);
        acc[g] = __builtin_amdgcn_mfma_f32_16x16x32_bf16(af, bfr, acc[g], 0, 0, 0);
      }
    }
    // epilogue: gates, state update, stores
    char* hnxt = (char*)hbuf + (cur ^ 1) * (BATCH * HDIM * 2);
#pragma unroll
    for (int i = 0; i < 4; ++i) {
      int row = wave * 16 + mrow + i;
      float pf = acc[0][i] + xp[0][i];
      float pi = acc[1][i] + xp[1][i];
      float pg = acc[2][i] + xp[2][i];
      float po = acc[3][i] + xp[3][i];
      float fg = sigf(pf), ig = sigf(pi), gg = tanh_fast(pg), og = sigf(po);
      float cn = fg * c_state[i] + ig * gg;
      c_state[i] = cn;
      float hn = og * tanh_fast(cn);
      out[((size_t)t * BATCH + row) * HDIM + hc0 + col] = hn;
      // h broadcast store via coherence point
      void* hp = hnxt + (row * HDIM + hc0 + col) * 2;
      unsigned hb = bfbits(hn);
      asm volatile("global_store_short %0, %1, off sc0 sc1" :: "v"(hp), "v"(hb) : "memory");
      if (t == T_STEPS - 1) {
        out_hx[row * HDIM + hc0 + col] = hn;
        out_cx[row * HDIM + hc0 + col] = cn;
      }
    }
    asm volatile("s_waitcnt vmcnt(0)" ::: "memory");  // this wave's h stores at LLC
    __syncthreads();                                   // all waves drained
    if (tid == 0 && t < T_STEPS - 1) {
      const int* fp = &flags[j];
      int nv = t + 1;
      asm volatile("global_store_dword %0, %1, off sc0 sc1" :: "v"(fp), "v"(nv) : "memory");
    }
  }
}

extern "C" void kernel_launch(void* const* d_in, const int* in_sizes, int n_in,
                              void* d_out, int out_size, void* d_ws, size_t ws_size,
                              hipStream_t stream) {
  const float* x   = (const float*)d_in[0];
  const float* Wf  = (const float*)d_in[1];
  const float* bf_ = (const float*)d_in[2];
  const float* Wi  = (const float*)d_in[3];
  const float* bi  = (const float*)d_in[4];
  const float* Wg  = (const float*)d_in[5];
  const float* bg  = (const float*)d_in[6];
  const float* Wo  = (const float*)d_in[7];
  const float* bo  = (const float*)d_in[8];

  char* ws = (char*)d_ws;
  __hip_bfloat16* xbf   = (__hip_bfloat16*)(ws);                 // 33,554,432 B
  __hip_bfloat16* wxbt  = (__hip_bfloat16*)(ws + 33554432);      //  2,097,152 B
  __hip_bfloat16* whbt  = (__hip_bfloat16*)(ws + 35651584);      //  2,097,152 B
  float*          bias  = (float*)         (ws + 37748736);      //      8,192 B
  __hip_bfloat16* xproj = (__hip_bfloat16*)(ws + 37756928);      // 134,217,728 B
  __hip_bfloat16* hbuf  = (__hip_bfloat16*)(ws + 171974656);     //    131,072 B
  int*            flags = (int*)           (ws + 172105728);     //        128 B

  k_prep <<<4096, 256, 0, stream>>>(Wf, bf_, Wi, bi, Wg, bg, Wo, bo,
                                    wxbt, whbt, bias, hbuf, flags);
  k_convx<<<8192, 256, 0, stream>>>(x, xbf);
  k_xproj<<<dim3(16, 256), 256, 0, stream>>>(xbf, wxbt, bias, xproj);
  k_recur<<<NWG, 256, 0, stream>>>(xproj, whbt, hbuf, (float*)d_out, flags);
}

// Round 3
// 2167.801 us; speedup vs baseline: 1.8272x; 1.3730x over previous
//
#include <hip/hip_runtime.h>
#include <hip/hip_bf16.h>
#include <stdint.h>
#include <stddef.h>

// LSTM: T=512, B=64, I=512, H=512.
// Phase 1: xproj GEMM (bf16 MFMA), output re-laid as [t][j=32][row=64][g=4][c=16]
//          so each recurrent wave reads a coalesced 8KB block per step.
// Phase 2: 128 INDEPENDENT waves (32 col-groups x 4 row-groups), 64-thr WGs.
//          Weights live in VGPRs (256 VGPRs/wave, loaded once) -- NO LDS AT ALL
//          (round 2 burned ~1.3us/step streaming the same 64KB from LDS).
//          h broadcast + per-wave flags via sc0 sc1 (coherent LLC path).

#define T_STEPS 512
#define BATCH   64
#define HDIM    512

using short8 = __attribute__((ext_vector_type(8))) short;  // 8 bf16 (4 VGPR) MFMA operand
using f32x4  = __attribute__((ext_vector_type(4))) float;  // MFMA accumulator
using int4v  = __attribute__((ext_vector_type(4))) int;
using int2v  = __attribute__((ext_vector_type(2))) int;

__device__ __forceinline__ void gload_lds16(const void* g, void* l) {
  __builtin_amdgcn_global_load_lds((const __attribute__((address_space(1))) void*)g,
                                   (__attribute__((address_space(3))) void*)l, 16, 0, 0);
}
__device__ __forceinline__ float sigf(float x) { return 1.0f / (1.0f + __expf(-x)); }
__device__ __forceinline__ float tanh_fast(float x) {
  x = fminf(fmaxf(x, -15.0f), 15.0f);
  float e = __expf(2.0f * x);
  return (e - 1.0f) / (e + 1.0f);
}
__device__ __forceinline__ short bfb(float f) {
  __hip_bfloat16 h = __float2bfloat16(f);
  short s; __builtin_memcpy(&s, &h, 2); return s;
}
__device__ __forceinline__ unsigned bfbits(float f) {
  __hip_bfloat16 h = __float2bfloat16(f);
  unsigned short s; __builtin_memcpy(&s, &h, 2); return (unsigned)s;
}
__device__ __forceinline__ float bf2f(unsigned u) {  // bf16 bits (low 16) -> f32
  return __builtin_bit_cast(float, u << 16);
}

// ---------------- prep: build Wx_bt/Wh_bt [2048][512] bf16, bias[2048], zero hbuf+flags
__global__ __launch_bounds__(256) void k_prep(
    const float* __restrict__ Wf, const float* __restrict__ bf_,
    const float* __restrict__ Wi, const float* __restrict__ bi,
    const float* __restrict__ Wg, const float* __restrict__ bg,
    const float* __restrict__ Wo, const float* __restrict__ bo,
    __hip_bfloat16* __restrict__ wxbt, __hip_bfloat16* __restrict__ whbt,
    float* __restrict__ bias, __hip_bfloat16* __restrict__ hbuf, int* __restrict__ flags)
{
  int idx = blockIdx.x * 256 + threadIdx.x;   // 4096 blocks -> 1,048,576 = 2048*512
  int row = idx >> 9;                          // 0..2047 (gate-major)
  int k   = idx & 511;
  int g = row >> 9, r = row & 511;
  const float* W = (g == 0) ? Wf : (g == 1) ? Wi : (g == 2) ? Wg : Wo;
  const float* B = (g == 0) ? bf_ : (g == 1) ? bi : (g == 2) ? bg : bo;
  wxbt[(size_t)row * 512 + k] = __float2bfloat16(W[(size_t)r * 1024 + k]);
  whbt[(size_t)row * 512 + k] = __float2bfloat16(W[(size_t)r * 1024 + 512 + k]);
  if (k == 0) bias[row] = B[r];
  if (idx < 2 * BATCH * HDIM) hbuf[idx] = __float2bfloat16(0.0f);  // both h buffers
  if (idx < 128) flags[idx] = 0;
}

// ---------------- convert x to bf16, 8 elems/thread
__global__ __launch_bounds__(256) void k_convx(const float* __restrict__ x,
                                               __hip_bfloat16* __restrict__ xbf)
{
  int idx = blockIdx.x * 256 + threadIdx.x;    // 8192 blocks
  const float4* p = (const float4*)x + (size_t)idx * 2;
  float4 a = p[0], b = p[1];
  short8 o;
  o[0]=bfb(a.x); o[1]=bfb(a.y); o[2]=bfb(a.z); o[3]=bfb(a.w);
  o[4]=bfb(b.x); o[5]=bfb(b.y); o[6]=bfb(b.z); o[7]=bfb(b.w);
  *(short8*)((short*)xbf + (size_t)idx * 8) = o;
}

// ---------------- phase 1 GEMM: [32768,512] x [512 -> 2048] (B^T layout), +bias
// Output re-laid: xproj[t][j][row][g][c]  (t=512, j=32 colgroups, row=64, g=4, c=16)
__global__ __launch_bounds__(256) void k_xproj(
    const __hip_bfloat16* __restrict__ xbf,   // [32768][512]
    const __hip_bfloat16* __restrict__ wxbt,  // [2048][512]
    const float* __restrict__ bias,           // [2048]
    __hip_bfloat16* __restrict__ xproj)       // [512][32][64][4][16]
{
  __shared__ __align__(16) short aT[128 * 64];
  __shared__ __align__(16) short bT[128 * 64];
  const int tid = threadIdx.x, lane = tid & 63, wave = tid >> 6;
  const int m0 = blockIdx.y * 128, n0 = blockIdx.x * 128;
  const int wr = wave >> 1, wc = wave & 1;

  f32x4 acc[4][4] = {};

  for (int s = 0; s < 8; ++s) {               // K=512, BK=64
    __syncthreads();
    const int kbyte = s * 128;
#pragma unroll
    for (int it = 0; it < 4; ++it) {
      int flat = it * 256 + tid;
      int row = flat >> 3, gr = flat & 7;
      int sgr = gr ^ (row & 7);
      const char* ga = (const char*)xbf  + (size_t)(m0 + row) * 1024 + kbyte + sgr * 16;
      const char* gb = (const char*)wxbt + (size_t)(n0 + row) * 1024 + kbyte + sgr * 16;
      gload_lds16(ga, (char*)aT + (it * 256 + wave * 64) * 16);
      gload_lds16(gb, (char*)bT + (it * 256 + wave * 64) * 16);
    }
    __syncthreads();
#pragma unroll
    for (int kk2 = 0; kk2 < 2; ++kk2) {
      short8 af[4], bfr[4];
#pragma unroll
      for (int mt = 0; mt < 4; ++mt) {
        int r = wr * 64 + mt * 16 + (lane & 15);
        int g = (kk2 * 4 + (lane >> 4)) ^ (r & 7);
        af[mt] = *(const short8*)((const char*)aT + r * 128 + g * 16);
      }
#pragma unroll
      for (int nt = 0; nt < 4; ++nt) {
        int r = wc * 64 + nt * 16 + (lane & 15);
        int g = (kk2 * 4 + (lane >> 4)) ^ (r & 7);
        bfr[nt] = *(const short8*)((const char*)bT + r * 128 + g * 16);
      }
#pragma unroll
      for (int mt = 0; mt < 4; ++mt)
#pragma unroll
        for (int nt = 0; nt < 4; ++nt)
          acc[mt][nt] = __builtin_amdgcn_mfma_f32_16x16x32_bf16(af[mt], bfr[nt], acc[mt][nt], 0, 0, 0);
    }
  }
  // epilogue: + bias, store bf16 into re-laid layout. C: col=lane&15, row=(lane>>4)*4+i
#pragma unroll
  for (int nt = 0; nt < 4; ++nt) {
    int n = n0 + wc * 64 + nt * 16 + (lane & 15);
    float bv = bias[n];
    int j2 = (n >> 4) & 31, g2 = n >> 9, c2 = n & 15;
#pragma unroll
    for (int mt = 0; mt < 4; ++mt)
#pragma unroll
      for (int i = 0; i < 4; ++i) {
        int m = m0 + wr * 64 + mt * 16 + (lane >> 4) * 4 + i;
        int tt = m >> 6, rr = m & 63;
        xproj[(((size_t)tt * 32 + j2) * 64 + rr) * 64 + g2 * 16 + c2] =
            __float2bfloat16(acc[mt][nt][i] + bv);
      }
  }
}

// ---------------- phase 2: 128 independent waves (64-thread WGs).
// Wave bid: j = bid>>2 owns h-cols [j*16,j*16+16) (64 gate-rows), w = bid&3 owns
// batch rows [w*16, w*16+16). Weights in VGPRs; no LDS; per-wave flags.
__global__ __launch_bounds__(64, 1) void k_recur(
    const __hip_bfloat16* __restrict__ xproj, // [512][32][64][4][16]
    const __hip_bfloat16* __restrict__ whbt,  // [2048][512]
    __hip_bfloat16* __restrict__ hbuf,        // [2][64][512]
    float* __restrict__ out,                  // outputs | hx | cx
    int* __restrict__ flags)                  // [128]
{
  const int lane = threadIdx.x;
  const int bid  = blockIdx.x;                 // 0..127
  const int j = bid >> 2, w = bid & 3;
  const int hc0 = j * 16, col = lane & 15, q = lane >> 4, mrow = q * 4;

  // B-fragments resident in VGPRs for the whole kernel (64 x short8 = 256 VGPR).
  // B[k][c] = whbt[g*512+hc0+c][k], per lane: c=lane&15, k=kk*32+q*8+0..7
  short8 breg[16][4];
#pragma unroll
  for (int kk = 0; kk < 16; ++kk)
#pragma unroll
    for (int g = 0; g < 4; ++g)
      breg[kk][g] = *(const short8*)((const char*)whbt +
                      ((size_t)(g * 512 + hc0 + col)) * 1024 + (size_t)kk * 64 + q * 16);

  float c_state[4] = {0.f, 0.f, 0.f, 0.f};
  float* out_hx = out + (size_t)T_STEPS * BATCH * HDIM;
  float* out_cx = out_hx + BATCH * HDIM;

  for (int t = 0; t < T_STEPS; ++t) {
    const int cur = t & 1;
    // ---- issue xp loads early (plain cached path); they fly during the poll
    const char* xpb = (const char*)xproj +
        (((size_t)t * 32 + j) * 4096 + (size_t)(w * 16 + mrow) * 64 + col) * 2;
    unsigned xpu[4][4];
#pragma unroll
    for (int g = 0; g < 4; ++g)
#pragma unroll
      for (int i = 0; i < 4; ++i) {
        const void* p = xpb + i * 128 + g * 32;
        asm volatile("global_load_ushort %0, %1, off"
                     : "=v"(xpu[g][i]) : "v"(p) : "memory");
      }
    // ---- poll all 128 per-wave flags (2 per lane, dwordx2). t=0 trivially ready.
    if (t > 0) {
      const int* fp = flags + lane * 2;
      int2v fv;
      do {
        asm volatile("global_load_dwordx2 %0, %1, off sc0 sc1\n\t"
                     "s_waitcnt vmcnt(0)"
                     : "=v"(fv) : "v"(fp) : "memory");
      } while ((fv[0] < t) || (fv[1] < t));
    }
    // ---- h^t loads (coherent LLC path)
    const char* hb = (const char*)hbuf + cur * (BATCH * HDIM * 2) +
                     (size_t)(w * 16 + (lane & 15)) * 1024 + q * 16;
    int4v araw[16];
#pragma unroll
    for (int kk = 0; kk < 16; ++kk) {
      const void* p = hb + kk * 64;
      asm volatile("global_load_dwordx4 %0, %1, off sc0 sc1"
                   : "=v"(araw[kk]) : "v"(p) : "memory");
    }
    asm volatile("s_waitcnt vmcnt(0)" ::: "memory");
    __builtin_amdgcn_sched_barrier(0);   // rule #18: keep MFMA after the drain

    f32x4 acc[4] = {};
#pragma unroll
    for (int kk = 0; kk < 16; ++kk) {
      short8 af = __builtin_bit_cast(short8, araw[kk]);
#pragma unroll
      for (int g = 0; g < 4; ++g)
        acc[g] = __builtin_amdgcn_mfma_f32_16x16x32_bf16(af, breg[kk][g], acc[g], 0, 0, 0);
    }

    // ---- epilogue: gates, state update
    float hnv[4], cnv[4];
#pragma unroll
    for (int i = 0; i < 4; ++i) {
      float pf = acc[0][i] + bf2f(xpu[0][i]);
      float pi = acc[1][i] + bf2f(xpu[1][i]);
      float pg = acc[2][i] + bf2f(xpu[2][i]);
      float po = acc[3][i] + bf2f(xpu[3][i]);
      float fg = sigf(pf), ig = sigf(pi), gg = tanh_fast(pg), og = sigf(po);
      float cn = fg * c_state[i] + ig * gg;
      c_state[i] = cn;
      cnv[i] = cn;
      hnv[i] = og * tanh_fast(cn);
    }
    // h stores FIRST (oldest in vmcnt FIFO), then out stores
    char* hnxt = (char*)hbuf + (cur ^ 1) * (BATCH * HDIM * 2) +
                 ((size_t)(w * 16 + mrow) * 512 + hc0 + col) * 2;
#pragma unroll
    for (int i = 0; i < 4; ++i) {
      unsigned hb16 = bfbits(hnv[i]);
      void* p = hnxt + i * 1024;
      asm volatile("global_store_short %0, %1, off sc0 sc1"
                   :: "v"(p), "v"(hb16) : "memory");
    }
    float* outb = out + ((size_t)t * BATCH + w * 16 + mrow) * HDIM + hc0 + col;
#pragma unroll
    for (int i = 0; i < 4; ++i) outb[(size_t)i * HDIM] = hnv[i];
    if (t == T_STEPS - 1) {
#pragma unroll
      for (int i = 0; i < 4; ++i) {
        out_hx[(size_t)(w * 16 + mrow + i) * HDIM + hc0 + col] = hnv[i];
        out_cx[(size_t)(w * 16 + mrow + i) * HDIM + hc0 + col] = cnv[i];
      }
    }
    // drain h stores to LLC, then publish this wave's flag
    asm volatile("s_waitcnt vmcnt(0)" ::: "memory");
    if (t < T_STEPS - 1 && lane == 0) {
      const int* fp2 = flags + bid;
      int nv = t + 1;
      asm volatile("global_store_dword %0, %1, off sc0 sc1"
                   :: "v"(fp2), "v"(nv) : "memory");
    }
  }
}

extern "C" void kernel_launch(void* const* d_in, const int* in_sizes, int n_in,
                              void* d_out, int out_size, void* d_ws, size_t ws_size,
                              hipStream_t stream) {
  const float* x   = (const float*)d_in[0];
  const float* Wf  = (const float*)d_in[1];
  const float* bf_ = (const float*)d_in[2];
  const float* Wi  = (const float*)d_in[3];
  const float* bi  = (const float*)d_in[4];
  const float* Wg  = (const float*)d_in[5];
  const float* bg  = (const float*)d_in[6];
  const float* Wo  = (const float*)d_in[7];
  const float* bo  = (const float*)d_in[8];

  char* ws = (char*)d_ws;
  __hip_bfloat16* xbf   = (__hip_bfloat16*)(ws);                 // 33,554,432 B
  __hip_bfloat16* wxbt  = (__hip_bfloat16*)(ws + 33554432);      //  2,097,152 B
  __hip_bfloat16* whbt  = (__hip_bfloat16*)(ws + 35651584);      //  2,097,152 B
  float*          bias  = (float*)         (ws + 37748736);      //      8,192 B
  __hip_bfloat16* xproj = (__hip_bfloat16*)(ws + 37756928);      // 134,217,728 B
  __hip_bfloat16* hbuf  = (__hip_bfloat16*)(ws + 171974656);     //    131,072 B
  int*            flags = (int*)           (ws + 172105728);     //        512 B

  k_prep <<<4096, 256, 0, stream>>>(Wf, bf_, Wi, bi, Wg, bg, Wo, bo,
                                    wxbt, whbt, bias, hbuf, flags);
  k_convx<<<8192, 256, 0, stream>>>(x, xbf);
  k_xproj<<<dim3(16, 256), 256, 0, stream>>>(xbf, wxbt, bias, xproj);
  k_recur<<<128, 64, 0, stream>>>(xproj, whbt, hbuf, (float*)d_out, flags);
}

// Round 6
// 1857.820 us; speedup vs baseline: 2.1320x; 1.1669x over previous
//
#include <hip/hip_runtime.h>
#include <hip/hip_bf16.h>
#include <stdint.h>
#include <stddef.h>

// LSTM: T=512, B=64, I=512, H=512.
// Phase 1: xproj GEMM (bf16 MFMA), output re-laid as [t][j=32][row=64][g=4][c=16].
// Phase 2: 128 independent waves (32 col-groups x 4 row-groups), 64-thr WGs.
//          R6 = R3-proven skeleton (system-scope sc0 sc1 handshake, per-lane
//          divergent spin, no asm-pinned registers, no cross-iteration prefetch:
//          every R4/R5 novelty that aborted is dropped) plus three safe edits:
//          (a) Wh slice re-loaded each step via PLAIN short8 loads at the TOP of
//              the iteration, before the poll ("memory"-clobbered sync asm pins
//              them there; they fly during the spin and hit L1 -- R3's VGPR=200
//              showed the compiler reloaded weights anyway, but post-poll and
//              serialized on the critical path),
//          (b) poll only own row-group's 32 flags (recurrence = 4 independent
//              groups), flags re-laid as [w*32+j],
//          (c) out/hx/cx stores after the flag publish (drained by next poll).

#define T_STEPS 512
#define BATCH   64
#define HDIM    512

using short8 = __attribute__((ext_vector_type(8))) short;  // 8 bf16 (4 VGPR) MFMA operand
using f32x4  = __attribute__((ext_vector_type(4))) float;  // MFMA accumulator
using int4v  = __attribute__((ext_vector_type(4))) int;

__device__ __forceinline__ void gload_lds16(const void* g, void* l) {
  __builtin_amdgcn_global_load_lds((const __attribute__((address_space(1))) void*)g,
                                   (__attribute__((address_space(3))) void*)l, 16, 0, 0);
}
__device__ __forceinline__ float sigf(float x) { return 1.0f / (1.0f + __expf(-x)); }
__device__ __forceinline__ float tanh_fast(float x) {
  x = fminf(fmaxf(x, -15.0f), 15.0f);
  float e = __expf(2.0f * x);
  return (e - 1.0f) / (e + 1.0f);
}
__device__ __forceinline__ short bfb(float f) {
  __hip_bfloat16 h = __float2bfloat16(f);
  short s; __builtin_memcpy(&s, &h, 2); return s;
}
__device__ __forceinline__ unsigned bfbits(float f) {
  __hip_bfloat16 h = __float2bfloat16(f);
  unsigned short s; __builtin_memcpy(&s, &h, 2); return (unsigned)s;
}
__device__ __forceinline__ float bf2f(unsigned u) {  // bf16 bits (low 16) -> f32
  return __builtin_bit_cast(float, u << 16);
}

// ---------------- prep: build Wx_bt/Wh_bt [2048][512] bf16, bias[2048], zero hbuf+flags
__global__ __launch_bounds__(256) void k_prep(
    const float* __restrict__ Wf, const float* __restrict__ bf_,
    const float* __restrict__ Wi, const float* __restrict__ bi,
    const float* __restrict__ Wg, const float* __restrict__ bg,
    const float* __restrict__ Wo, const float* __restrict__ bo,
    __hip_bfloat16* __restrict__ wxbt, __hip_bfloat16* __restrict__ whbt,
    float* __restrict__ bias, __hip_bfloat16* __restrict__ hbuf, int* __restrict__ flags)
{
  int idx = blockIdx.x * 256 + threadIdx.x;   // 4096 blocks -> 1,048,576 = 2048*512
  int row = idx >> 9;                          // 0..2047 (gate-major)
  int k   = idx & 511;
  int g = row >> 9, r = row & 511;
  const float* W = (g == 0) ? Wf : (g == 1) ? Wi : (g == 2) ? Wg : Wo;
  const float* B = (g == 0) ? bf_ : (g == 1) ? bi : (g == 2) ? bg : bo;
  wxbt[(size_t)row * 512 + k] = __float2bfloat16(W[(size_t)r * 1024 + k]);
  whbt[(size_t)row * 512 + k] = __float2bfloat16(W[(size_t)r * 1024 + 512 + k]);
  if (k == 0) bias[row] = B[r];
  if (idx < 2 * BATCH * HDIM) hbuf[idx] = __float2bfloat16(0.0f);  // both h buffers
  if (idx < 128) flags[idx] = 0;
}

// ---------------- convert x to bf16, 8 elems/thread
__global__ __launch_bounds__(256) void k_convx(const float* __restrict__ x,
                                               __hip_bfloat16* __restrict__ xbf)
{
  int idx = blockIdx.x * 256 + threadIdx.x;    // 8192 blocks
  const float4* p = (const float4*)x + (size_t)idx * 2;
  float4 a = p[0], b = p[1];
  short8 o;
  o[0]=bfb(a.x); o[1]=bfb(a.y); o[2]=bfb(a.z); o[3]=bfb(a.w);
  o[4]=bfb(b.x); o[5]=bfb(b.y); o[6]=bfb(b.z); o[7]=bfb(b.w);
  *(short8*)((short*)xbf + (size_t)idx * 8) = o;
}

// ---------------- phase 1 GEMM: [32768,512] x [512 -> 2048] (B^T layout), +bias
// Output re-laid: xproj[t][j][row][g][c]  (t=512, j=32 colgroups, row=64, g=4, c=16)
__global__ __launch_bounds__(256) void k_xproj(
    const __hip_bfloat16* __restrict__ xbf,   // [32768][512]
    const __hip_bfloat16* __restrict__ wxbt,  // [2048][512]
    const float* __restrict__ bias,           // [2048]
    __hip_bfloat16* __restrict__ xproj)       // [512][32][64][4][16]
{
  __shared__ __align__(16) short aT[128 * 64];
  __shared__ __align__(16) short bT[128 * 64];
  const int tid = threadIdx.x, lane = tid & 63, wave = tid >> 6;
  const int m0 = blockIdx.y * 128, n0 = blockIdx.x * 128;
  const int wr = wave >> 1, wc = wave & 1;

  f32x4 acc[4][4] = {};

  for (int s = 0; s < 8; ++s) {               // K=512, BK=64
    __syncthreads();
    const int kbyte = s * 128;
#pragma unroll
    for (int it = 0; it < 4; ++it) {
      int flat = it * 256 + tid;
      int row = flat >> 3, gr = flat & 7;
      int sgr = gr ^ (row & 7);
      const char* ga = (const char*)xbf  + (size_t)(m0 + row) * 1024 + kbyte + sgr * 16;
      const char* gb = (const char*)wxbt + (size_t)(n0 + row) * 1024 + kbyte + sgr * 16;
      gload_lds16(ga, (char*)aT + (it * 256 + wave * 64) * 16);
      gload_lds16(gb, (char*)bT + (it * 256 + wave * 64) * 16);
    }
    __syncthreads();
#pragma unroll
    for (int kk2 = 0; kk2 < 2; ++kk2) {
      short8 af[4], bfr[4];
#pragma unroll
      for (int mt = 0; mt < 4; ++mt) {
        int r = wr * 64 + mt * 16 + (lane & 15);
        int g = (kk2 * 4 + (lane >> 4)) ^ (r & 7);
        af[mt] = *(const short8*)((const char*)aT + r * 128 + g * 16);
      }
#pragma unroll
      for (int nt = 0; nt < 4; ++nt) {
        int r = wc * 64 + nt * 16 + (lane & 15);
        int g = (kk2 * 4 + (lane >> 4)) ^ (r & 7);
        bfr[nt] = *(const short8*)((const char*)bT + r * 128 + g * 16);
      }
#pragma unroll
      for (int mt = 0; mt < 4; ++mt)
#pragma unroll
        for (int nt = 0; nt < 4; ++nt)
          acc[mt][nt] = __builtin_amdgcn_mfma_f32_16x16x32_bf16(af[mt], bfr[nt], acc[mt][nt], 0, 0, 0);
    }
  }
  // epilogue: + bias, store bf16 into re-laid layout. C: col=lane&15, row=(lane>>4)*4+i
#pragma unroll
  for (int nt = 0; nt < 4; ++nt) {
    int n = n0 + wc * 64 + nt * 16 + (lane & 15);
    float bv = bias[n];
    int j2 = (n >> 4) & 31, g2 = n >> 9, c2 = n & 15;
#pragma unroll
    for (int mt = 0; mt < 4; ++mt)
#pragma unroll
      for (int i = 0; i < 4; ++i) {
        int m = m0 + wr * 64 + mt * 16 + (lane >> 4) * 4 + i;
        int tt = m >> 6, rr = m & 63;
        xproj[(((size_t)tt * 32 + j2) * 64 + rr) * 64 + g2 * 16 + c2] =
            __float2bfloat16(acc[mt][nt][i] + bv);
      }
  }
}

// ---------------- phase 2: 128 independent waves (64-thread WGs).
// Wave bid: j = bid>>2 owns h-cols [j*16,j*16+16); w = bid&3 owns batch rows
// [w*16,w*16+16). flags[w*32+j]. All cross-wave traffic via sc0 sc1 (LLC).
__global__ __launch_bounds__(64, 1) void k_recur(
    const __hip_bfloat16* __restrict__ xproj, // [512][32][64][4][16]
    const __hip_bfloat16* __restrict__ whbt,  // [2048][512]
    __hip_bfloat16* __restrict__ hbuf,        // [2][64][512]
    float* __restrict__ out,                  // outputs | hx | cx
    int* __restrict__ flags)                  // [128], layout w*32+j
{
  const int lane = threadIdx.x;
  const int bid  = blockIdx.x;                 // 0..127
  const int j = bid >> 2, w = bid & 3;
  const int hc0 = j * 16, col = lane & 15, q = lane >> 4, mrow = q * 4;

  float c_state[4] = {0.f, 0.f, 0.f, 0.f};
  float* out_hx = out + (size_t)T_STEPS * BATCH * HDIM;
  float* out_cx = out_hx + BATCH * HDIM;

  // invariant base for this wave's Wh slice: B[k][c]=whbt[g*512+hc0+c][k],
  // per lane c=lane&15, k=kk*32+q*8+0..7
  const char* wbase = (const char*)whbt + ((size_t)(hc0 + col)) * 1024 + q * 16;

  for (int t = 0; t < T_STEPS; ++t) {
    const int cur = t & 1;
    // ---- (a) Wh slice loads: plain, L1-hot, issued BEFORE the poll so they
    // fly during the spin. "memory" clobbers below pin them here.
    short8 bw[16][4];
#pragma unroll
    for (int kk = 0; kk < 16; ++kk)
#pragma unroll
      for (int gg = 0; gg < 4; ++gg)
        bw[kk][gg] = *(const short8*)(wbase + (size_t)gg * 524288 + (size_t)kk * 64);

    // ---- xp loads, also pre-poll (R3-proven asm form)
    const char* xpb = (const char*)xproj +
        (((size_t)t * 32 + j) * 4096 + (size_t)(w * 16 + mrow) * 64 + col) * 2;
    unsigned xpu[4][4];
#pragma unroll
    for (int g = 0; g < 4; ++g)
#pragma unroll
      for (int i = 0; i < 4; ++i) {
        const void* p = xpb + i * 128 + g * 32;
        asm volatile("global_load_ushort %0, %1, off"
                     : "=v"(xpu[g][i]) : "v"(p) : "memory");
      }
    // ---- (b) poll own row-group's 32 flags (per-lane divergent spin, R3 form)
    if (t > 0) {
      const int* fp = flags + w * 32 + (lane & 31);
      int fv;
      do {
        asm volatile("global_load_dword %0, %1, off sc0 sc1\n\ts_waitcnt vmcnt(0)"
                     : "=v"(fv) : "v"(fp) : "memory");
      } while (fv < t);
    }
    // ---- h^t loads (coherent LLC path)
    const char* hb = (const char*)hbuf + cur * (BATCH * HDIM * 2) +
                     (size_t)(w * 16 + (lane & 15)) * 1024 + q * 16;
    int4v araw[16];
#pragma unroll
    for (int kk = 0; kk < 16; ++kk) {
      const void* p = hb + kk * 64;
      asm volatile("global_load_dwordx4 %0, %1, off sc0 sc1"
                   : "=v"(araw[kk]) : "v"(p) : "memory");
    }
    asm volatile("s_waitcnt vmcnt(0)" ::: "memory");
    __builtin_amdgcn_sched_barrier(0);   // rule #18: keep MFMA after the drain

    f32x4 acc[4] = {};
#pragma unroll
    for (int kk = 0; kk < 16; ++kk) {
      short8 af = __builtin_bit_cast(short8, araw[kk]);
#pragma unroll
      for (int gg = 0; gg < 4; ++gg)
        acc[gg] = __builtin_amdgcn_mfma_f32_16x16x32_bf16(af, bw[kk][gg], acc[gg], 0, 0, 0);
    }

    // ---- epilogue: gates, state update (xpu drained by the vmcnt(0) above)
    float hnv[4], cnv[4];
#pragma unroll
    for (int i = 0; i < 4; ++i) {
      float pf = acc[0][i] + bf2f(xpu[0][i]);
      float pi = acc[1][i] + bf2f(xpu[1][i]);
      float pg = acc[2][i] + bf2f(xpu[2][i]);
      float po = acc[3][i] + bf2f(xpu[3][i]);
      float fg = sigf(pf), ig = sigf(pi), gg2 = tanh_fast(pg), og = sigf(po);
      float cn = fg * c_state[i] + ig * gg2;
      c_state[i] = cn;
      cnv[i] = cn;
      hnv[i] = og * tanh_fast(cn);
    }
    // ---- h stores -> drain -> flag publish; out stores AFTER (drained by
    // the next iteration's poll vmcnt(0), off the publish path)
    char* hnxt = (char*)hbuf + (cur ^ 1) * (BATCH * HDIM * 2) +
                 ((size_t)(w * 16 + mrow) * 512 + hc0 + col) * 2;
#pragma unroll
    for (int i = 0; i < 4; ++i) {
      unsigned hb16 = bfbits(hnv[i]);
      void* p = hnxt + i * 1024;
      asm volatile("global_store_short %0, %1, off sc0 sc1"
                   :: "v"(p), "v"(hb16) : "memory");
    }
    asm volatile("s_waitcnt vmcnt(0)" ::: "memory");  // h stores at LLC
    if (t < T_STEPS - 1 && lane == 0) {
      int nv = t + 1;
      int* fp2 = flags + w * 32 + j;
      asm volatile("global_store_dword %0, %1, off sc0 sc1"
                   :: "v"(fp2), "v"(nv) : "memory");
    }
    float* outb = out + ((size_t)t * BATCH + w * 16 + mrow) * HDIM + hc0 + col;
#pragma unroll
    for (int i = 0; i < 4; ++i) outb[(size_t)i * HDIM] = hnv[i];
    if (t == T_STEPS - 1) {
#pragma unroll
      for (int i = 0; i < 4; ++i) {
        out_hx[(size_t)(w * 16 + mrow + i) * HDIM + hc0 + col] = hnv[i];
        out_cx[(size_t)(w * 16 + mrow + i) * HDIM + hc0 + col] = cnv[i];
      }
    }
  }
}

extern "C" void kernel_launch(void* const* d_in, const int* in_sizes, int n_in,
                              void* d_out, int out_size, void* d_ws, size_t ws_size,
                              hipStream_t stream) {
  const float* x   = (const float*)d_in[0];
  const float* Wf  = (const float*)d_in[1];
  const float* bf_ = (const float*)d_in[2];
  const float* Wi  = (const float*)d_in[3];
  const float* bi  = (const float*)d_in[4];
  const float* Wg  = (const float*)d_in[5];
  const float* bg  = (const float*)d_in[6];
  const float* Wo  = (const float*)d_in[7];
  const float* bo  = (const float*)d_in[8];

  char* ws = (char*)d_ws;
  __hip_bfloat16* xbf   = (__hip_bfloat16*)(ws);                 // 33,554,432 B
  __hip_bfloat16* wxbt  = (__hip_bfloat16*)(ws + 33554432);      //  2,097,152 B
  __hip_bfloat16* whbt  = (__hip_bfloat16*)(ws + 35651584);      //  2,097,152 B
  float*          bias  = (float*)         (ws + 37748736);      //      8,192 B
  __hip_bfloat16* xproj = (__hip_bfloat16*)(ws + 37756928);      // 134,217,728 B
  __hip_bfloat16* hbuf  = (__hip_bfloat16*)(ws + 171974656);     //    131,072 B
  int*            flags = (int*)           (ws + 172105728);     //        512 B

  k_prep <<<4096, 256, 0, stream>>>(Wf, bf_, Wi, bi, Wg, bg, Wo, bo,
                                    wxbt, whbt, bias, hbuf, flags);
  k_convx<<<8192, 256, 0, stream>>>(x, xbf);
  k_xproj<<<dim3(16, 256), 256, 0, stream>>>(xbf, wxbt, bias, xproj);
  k_recur<<<128, 64, 0, stream>>>(xproj, whbt, hbuf, (float*)d_out, flags);
}